// Round 3
// baseline (1523.682 us; speedup 1.0000x reference)
//
#include <hip/hip_runtime.h>
#include <stdint.h>

#define D_MODEL 1024
#define EXP_D   4096
#define NE      8
#define NTOK    8192
#define BMT     128
#define MAX_TILES 136
#define NS_MAX  17408   // MAX_TILES*128

typedef __attribute__((ext_vector_type(8))) short short8;
typedef __attribute__((ext_vector_type(4))) float f32x4;
typedef __attribute__((ext_vector_type(4))) unsigned short us4;

// ---- workspace layout (bytes) ----
#define WS_COUNTS    0          // int[8]
#define WS_CURSORS   32         // int[8]
#define WS_PADOFF    64         // int[16]
#define WS_META      128        // int[32], meta[0]=ntiles
#define WS_TILE_E    256        // int[256]
#define WS_PP        4096       // float[2048*8]
#define WS_TOP_E     69632      // int[16384]
#define WS_TOP_W     135168     // float[16384]
#define WS_SLOT_W    270336     // float[17408]
#define WS_TOK_SLOT  339968     // int[16384]
#define WS_XG        405504     // bf16 [17408][1024]  (Yb aliases this)
#define WS_HB        36057088   // bf16 [17408][4096]
#define WS_WB        178663424  // bf16 [8][4096][1024] weights -> ends 245,772,288

#define LDSBUF 49152            // 48KB per buffer: A 16KB + B 32KB
#define LDS_TOTAL 147456        // 3 buffers

__device__ __forceinline__ unsigned short f2bf(float f){
  __bf16 h = (__bf16)f;
  return __builtin_bit_cast(unsigned short, h);
}
__device__ __forceinline__ float bf2f(unsigned short u){
  unsigned int v = ((unsigned int)u) << 16;
  return __builtin_bit_cast(float, v);
}
__device__ __forceinline__ void gl_lds16(const void* g, void* l){
  __builtin_amdgcn_global_load_lds((const __attribute__((address_space(1))) unsigned int*)g,
                                   (__attribute__((address_space(3))) unsigned int*)l,
                                   16, 0, 0);
}

// ---------------- init: zero 64-int header ----------------
__global__ void init_kernel(int* __restrict__ hdr){
  if (threadIdx.x < 64) hdr[threadIdx.x] = 0;
}

// ---------------- weight fp32 -> bf16 convert ----------------
__global__ __launch_bounds__(256) void cvt_kernel(const float* __restrict__ W,
                                                  unsigned short* __restrict__ Wb){
  const int n4 = NE*EXP_D*D_MODEL/4;
  for (int i = blockIdx.x*256 + threadIdx.x; i < n4; i += gridDim.x*256){
    const float4 v = *(const float4*)&W[(size_t)i*4];
    us4 o; o[0]=f2bf(v.x); o[1]=f2bf(v.y); o[2]=f2bf(v.z); o[3]=f2bf(v.w);
    *(us4*)&Wb[(size_t)i*4] = o;
  }
}

// ---------------- router: one wave per token ----------------
__global__ __launch_bounds__(256) void router_kernel(
    const float* __restrict__ x, const float* __restrict__ Wr,
    const float* __restrict__ br,
    int* __restrict__ counts, int* __restrict__ top_e, float* __restrict__ top_w,
    float* __restrict__ pp)
{
  __shared__ float WrS[NE*D_MODEL];
  __shared__ float wprob[4][NE];
  const int tid = threadIdx.x;
#pragma unroll
  for (int i=0;i<8;++i){
    int j = (tid + i*256)*4;
    *(float4*)&WrS[j] = *(const float4*)&Wr[j];
  }
  __syncthreads();
  const int w = tid>>6, lane = tid&63;
  const int t = blockIdx.x*4 + w;
  const float* xt = x + (size_t)t*D_MODEL;
  float accv[8] = {0,0,0,0,0,0,0,0};
#pragma unroll
  for (int i=0;i<4;++i){
    const int k = i*256 + lane*4;
    const float4 xv = *(const float4*)&xt[k];
#pragma unroll
    for (int e=0;e<8;++e){
      const float4 wv = *(const float4*)&WrS[e*D_MODEL + k];
      accv[e] += xv.x*wv.x + xv.y*wv.y + xv.z*wv.z + xv.w*wv.w;
    }
  }
#pragma unroll
  for (int m=32;m>0;m>>=1){
#pragma unroll
    for (int e=0;e<8;++e) accv[e] += __shfl_xor(accv[e], m, 64);
  }
  if (lane==0){
    float lg[8];
#pragma unroll
    for (int e=0;e<8;++e) lg[e] = accv[e] + br[e];
    float mx = lg[0];
#pragma unroll
    for (int e=1;e<8;++e) mx = fmaxf(mx, lg[e]);
    float p[8]; float s=0.f;
#pragma unroll
    for (int e=0;e<8;++e){ p[e] = __expf(lg[e]-mx); s += p[e]; }
    const float inv = 1.f/s;
#pragma unroll
    for (int e=0;e<8;++e){ p[e] *= inv; wprob[w][e] = p[e]; }
    int i1=0; float p1v=p[0];
#pragma unroll
    for (int e=1;e<8;++e) if (p[e] > p1v){ p1v=p[e]; i1=e; }
    int i2=-1; float p2v=-1.f;
#pragma unroll
    for (int e=0;e<8;++e) if (e!=i1 && p[e] > p2v){ p2v=p[e]; i2=e; }
    const float rn = 1.f/(p1v+p2v);
    top_e[2*t]   = i1; top_w[2*t]   = p1v*rn;
    top_e[2*t+1] = i2; top_w[2*t+1] = p2v*rn;
    atomicAdd(&counts[i1],1);
    atomicAdd(&counts[i2],1);
  }
  __syncthreads();
  if (tid<8){
    pp[blockIdx.x*8+tid] = wprob[0][tid]+wprob[1][tid]+wprob[2][tid]+wprob[3][tid];
  }
}

// ---------------- prefix: tile table + aux loss ----------------
__global__ void prefix_kernel(int* __restrict__ wsI, const float* __restrict__ pp,
                              float* __restrict__ aux_out){
  const int tid = threadIdx.x;
  __shared__ float dev2[8];
  if (tid==0){
    int* counts = wsI + 0;
    int* padoff = wsI + 16;
    int* meta   = wsI + 32;
    int* tileE  = wsI + 64;
    int nt = 0;
    for (int e=0;e<NE;++e){
      padoff[e] = nt*BMT;
      int tiles = (counts[e] + BMT - 1) >> 7;
      for (int i=0;i<tiles;++i) tileE[nt++] = e;
    }
    meta[0] = nt;
  }
  if (tid<8){
    float s=0.f;
    for (int b=0;b<NTOK/4;++b) s += pp[b*8+tid];
    float d = s*(1.f/(float)NTOK) - 0.125f;
    dev2[tid] = d*d;
  }
  __syncthreads();
  if (tid==0){
    float a=0.f;
#pragma unroll
    for (int e=0;e<8;++e) a += dev2[e];
    aux_out[0] = a;
  }
}

// ---------------- fused scatter+gather: wave per token ----------------
__global__ __launch_bounds__(256) void scatgath_kernel(
    const float* __restrict__ x, const int* __restrict__ top_e,
    const float* __restrict__ top_w,
    int* __restrict__ cursors, const int* __restrict__ padoff,
    float* __restrict__ slot_w, int* __restrict__ tok_slot,
    unsigned short* __restrict__ Xg)
{
  const int w = threadIdx.x>>6, lane = threadIdx.x&63;
  const int t = blockIdx.x*4 + w;
  int s0 = 0, s1 = 0;
  if (lane==0){
    const int e0 = top_e[2*t], e1 = top_e[2*t+1];
    s0 = padoff[e0] + atomicAdd(&cursors[e0],1);
    s1 = padoff[e1] + atomicAdd(&cursors[e1],1);
    slot_w[s0] = top_w[2*t]; slot_w[s1] = top_w[2*t+1];
    tok_slot[2*t] = s0; tok_slot[2*t+1] = s1;
  }
  s0 = __shfl(s0, 0, 64); s1 = __shfl(s1, 0, 64);
  us4 o[4];
#pragma unroll
  for (int i=0;i<4;++i){
    const float4 v = *(const float4*)&x[(size_t)t*D_MODEL + i*256 + lane*4];
    o[i][0]=f2bf(v.x); o[i][1]=f2bf(v.y); o[i][2]=f2bf(v.z); o[i][3]=f2bf(v.w);
  }
#pragma unroll
  for (int i=0;i<4;++i) *(us4*)&Xg[(size_t)s0*D_MODEL + i*256 + lane*4] = o[i];
#pragma unroll
  for (int i=0;i<4;++i) *(us4*)&Xg[(size_t)s1*D_MODEL + i*256 + lane*4] = o[i];
}

// ---------------- grouped GEMM: 128x256 tile, BK=64, 8 waves, 3-buf pipeline ----------------
// C[m][n] = sum_k A[m][k] * W[e][n][k]  (+bias; G1: relu; G2: *slot_w[m])
#define VM6   asm volatile("s_waitcnt vmcnt(6)" ::: "memory")
#define VM0   asm volatile("s_waitcnt vmcnt(0)" ::: "memory")
#define LGKM0 do{ asm volatile("s_waitcnt lgkmcnt(0)" ::: "memory"); __builtin_amdgcn_sched_barrier(0); }while(0)
#define FENCE asm volatile("" ::: "memory")

template<int KT, int NT, bool G2>
__global__ __launch_bounds__(512,1) void moe_gemm8(
    const unsigned short* __restrict__ A,
    const unsigned short* __restrict__ Wb,
    const float* __restrict__ bias,
    unsigned short* __restrict__ Cout,
    const int* __restrict__ tileE,
    const int* __restrict__ meta,
    const float* __restrict__ slotw)
{
  constexpr int NX = NT/256;
  constexpr int TOTAL = NX*MAX_TILES;
  constexpr int Q = TOTAL/8, R = TOTAL%8;
  constexpr int NTILES = KT/64;
  // bijective XCD chunk swizzle (N-fastest within chunk -> A-tile L2 reuse)
  const int lid = blockIdx.x;
  const int xc = lid & 7, jj = lid >> 3;
  const int tsw = xc*Q + (xc < R ? xc : R) + jj;
  const int mtile = tsw / NX, ntile = tsw - mtile*NX;
  if (mtile >= meta[0]) return;

  extern __shared__ char smem[];
  const int tid  = threadIdx.x;
  const int w    = tid >> 6, lane = tid & 63;
  const int e    = tileE[mtile];
  const int m0   = mtile * BMT;
  const int n0   = ntile * 256;

  // staging: per instr, wave w covers rows base+w*8+(lane>>3); 16B chunk (lane&7)
  // LDS linear; global source pre-swizzled: logical chunk = phys ^ (row&7), row&7 = lane>>3
  const int srow = w*8 + (lane>>3);
  const int scol = ((lane&7) ^ (lane>>3)) * 8;   // elements
  const unsigned short* Aps = A  + (size_t)(m0 + srow)*KT + scol;
  const unsigned short* Bps = Wb + (size_t)e*NT*KT + (size_t)(n0 + srow)*KT + scol;

#define STG3A(bufc, kbe) do{ \
    gl_lds16(Aps + (kbe),                smem + (size_t)(bufc)*LDSBUF + (w*8)*128); \
    gl_lds16(Aps + (size_t)64*KT + (kbe), smem + (size_t)(bufc)*LDSBUF + (64 + w*8)*128); \
    gl_lds16(Bps + (kbe),                smem + (size_t)(bufc)*LDSBUF + 16384 + (w*8)*128); \
  }while(0)
#define STG3B(bufc, kbe) do{ \
    gl_lds16(Bps + (size_t)64*KT  + (kbe), smem + (size_t)(bufc)*LDSBUF + 16384 + (64  + w*8)*128); \
    gl_lds16(Bps + (size_t)128*KT + (kbe), smem + (size_t)(bufc)*LDSBUF + 16384 + (128 + w*8)*128); \
    gl_lds16(Bps + (size_t)192*KT + (kbe), smem + (size_t)(bufc)*LDSBUF + 16384 + (192 + w*8)*128); \
  }while(0)

  // fragment read addressing
  const int wm = w >> 2, wn = w & 3;       // 2M x 4N waves, per-wave 64x64
  const int r16 = lane & 15, kg = lane >> 4, l7 = lane & 7;
  const int aoff = (wm*64 + r16)*128;          // + fm*2048 + chunk*16
  const int boff = 16384 + (wn*64 + r16)*128;  // + fc*2048 + chunk*16

  f32x4 acc[4][4];
#pragma unroll
  for (int i=0;i<4;++i)
#pragma unroll
    for (int j=0;j<4;++j) acc[i][j] = (f32x4){0.f,0.f,0.f,0.f};

#define PHASE(sb, KK, STG_STMT, WAIT_STMT) do{ \
    const int ch = (((KK)*4 + kg) ^ l7) * 16; \
    short8 af0 = *(const short8*)((sb) + aoff + 0*2048 + ch); \
    short8 af1 = *(const short8*)((sb) + aoff + 1*2048 + ch); \
    short8 af2 = *(const short8*)((sb) + aoff + 2*2048 + ch); \
    short8 af3 = *(const short8*)((sb) + aoff + 3*2048 + ch); \
    short8 bv0 = *(const short8*)((sb) + boff + 0*2048 + ch); \
    short8 bv1 = *(const short8*)((sb) + boff + 1*2048 + ch); \
    short8 bv2 = *(const short8*)((sb) + boff + 2*2048 + ch); \
    short8 bv3 = *(const short8*)((sb) + boff + 3*2048 + ch); \
    STG_STMT; WAIT_STMT; FENCE; \
    __builtin_amdgcn_s_barrier(); \
    LGKM0; \
    __builtin_amdgcn_s_setprio(1); \
    acc[0][0]=__builtin_amdgcn_mfma_f32_16x16x32_bf16(bv0,af0,acc[0][0],0,0,0); \
    acc[0][1]=__builtin_amdgcn_mfma_f32_16x16x32_bf16(bv1,af0,acc[0][1],0,0,0); \
    acc[0][2]=__builtin_amdgcn_mfma_f32_16x16x32_bf16(bv2,af0,acc[0][2],0,0,0); \
    acc[0][3]=__builtin_amdgcn_mfma_f32_16x16x32_bf16(bv3,af0,acc[0][3],0,0,0); \
    acc[1][0]=__builtin_amdgcn_mfma_f32_16x16x32_bf16(bv0,af1,acc[1][0],0,0,0); \
    acc[1][1]=__builtin_amdgcn_mfma_f32_16x16x32_bf16(bv1,af1,acc[1][1],0,0,0); \
    acc[1][2]=__builtin_amdgcn_mfma_f32_16x16x32_bf16(bv2,af1,acc[1][2],0,0,0); \
    acc[1][3]=__builtin_amdgcn_mfma_f32_16x16x32_bf16(bv3,af1,acc[1][3],0,0,0); \
    acc[2][0]=__builtin_amdgcn_mfma_f32_16x16x32_bf16(bv0,af2,acc[2][0],0,0,0); \
    acc[2][1]=__builtin_amdgcn_mfma_f32_16x16x32_bf16(bv1,af2,acc[2][1],0,0,0); \
    acc[2][2]=__builtin_amdgcn_mfma_f32_16x16x32_bf16(bv2,af2,acc[2][2],0,0,0); \
    acc[2][3]=__builtin_amdgcn_mfma_f32_16x16x32_bf16(bv3,af2,acc[2][3],0,0,0); \
    acc[3][0]=__builtin_amdgcn_mfma_f32_16x16x32_bf16(bv0,af3,acc[3][0],0,0,0); \
    acc[3][1]=__builtin_amdgcn_mfma_f32_16x16x32_bf16(bv1,af3,acc[3][1],0,0,0); \
    acc[3][2]=__builtin_amdgcn_mfma_f32_16x16x32_bf16(bv2,af3,acc[3][2],0,0,0); \
    acc[3][3]=__builtin_amdgcn_mfma_f32_16x16x32_bf16(bv3,af3,acc[3][3],0,0,0); \
    __builtin_amdgcn_s_setprio(0); \
    __builtin_amdgcn_sched_barrier(0); \
    __builtin_amdgcn_s_barrier(); \
  }while(0)

  // prologue: stage tiles 0 and 1
  STG3A(0, 0); STG3B(0, 0);
  STG3A(1, 64); STG3B(1, 64);
  VM6; FENCE;
  __builtin_amdgcn_s_barrier();

  int cur = 0, stg = 2;
  for (int tt = 0; tt < NTILES-2; ++tt){
    const int kbn = (tt+2)*64;
    const char* sb = smem + (size_t)cur*LDSBUF;
    PHASE(sb, 0, STG3A(stg, kbn), (void)0);
    PHASE(sb, 1, STG3B(stg, kbn), VM6);
    cur = (cur==2)?0:cur+1;
    stg = (stg==2)?0:stg+1;
  }
  { // tile NTILES-2: no stage; drain remaining loads at ph1
    const char* sb = smem + (size_t)cur*LDSBUF;
    PHASE(sb, 0, (void)0, (void)0);
    PHASE(sb, 1, (void)0, VM0);
    cur = (cur==2)?0:cur+1;
  }
  { // tile NTILES-1: no stage, no wait
    const char* sb = smem + (size_t)cur*LDSBUF;
    PHASE(sb, 0, (void)0, (void)0);
    PHASE(sb, 1, (void)0, (void)0);
  }

  // epilogue: lane holds 4 consecutive n per fragment (swapped-operand layout)
  const int mrow = lane & 15, ng4 = (lane >> 4)*4;
#pragma unroll
  for (int fm=0; fm<4; ++fm){
    const int m = m0 + wm*64 + fm*16 + mrow;
    float wg = 0.f;
    if (G2) wg = slotw[m];
#pragma unroll
    for (int fc=0; fc<4; ++fc){
      const int nb = n0 + wn*64 + fc*16 + ng4;
      const float4 bv = *(const float4*)&bias[(size_t)e*NT + nb];
      float q0 = acc[fm][fc][0] + bv.x;
      float q1 = acc[fm][fc][1] + bv.y;
      float q2 = acc[fm][fc][2] + bv.z;
      float q3 = acc[fm][fc][3] + bv.w;
      if (!G2){
        q0=fmaxf(q0,0.f); q1=fmaxf(q1,0.f); q2=fmaxf(q2,0.f); q3=fmaxf(q3,0.f);
      } else {
        q0*=wg; q1*=wg; q2*=wg; q3*=wg;
      }
      us4 o; o[0]=f2bf(q0); o[1]=f2bf(q1); o[2]=f2bf(q2); o[3]=f2bf(q3);
      *(us4*)&Cout[(size_t)m*NT + nb] = o;
    }
  }
#undef PHASE
#undef STG3A
#undef STG3B
}

// ---------------- combine: out[t] = Y[slot0] + Y[slot1] ----------------
__global__ __launch_bounds__(256) void combine_kernel(
    const unsigned short* __restrict__ Yb, const int* __restrict__ tok_slot,
    float* __restrict__ out)
{
  const int t = blockIdx.x;
  const int tid = threadIdx.x;
  const int s0 = tok_slot[2*t], s1 = tok_slot[2*t+1];
  const us4 a = *(const us4*)&Yb[(size_t)s0*D_MODEL + tid*4];
  const us4 b = *(const us4*)&Yb[(size_t)s1*D_MODEL + tid*4];
  float4 o;
  o.x = bf2f(a[0]) + bf2f(b[0]);
  o.y = bf2f(a[1]) + bf2f(b[1]);
  o.z = bf2f(a[2]) + bf2f(b[2]);
  o.w = bf2f(a[3]) + bf2f(b[3]);
  *(float4*)&out[(size_t)t*D_MODEL + tid*4] = o;
}

extern "C" void kernel_launch(void* const* d_in, const int* in_sizes, int n_in,
                              void* d_out, int out_size, void* d_ws, size_t ws_size,
                              hipStream_t stream)
{
  const float* x  = (const float*)d_in[0];
  const float* Wr = (const float*)d_in[1];
  const float* br = (const float*)d_in[2];
  const float* W1 = (const float*)d_in[3];
  const float* b1 = (const float*)d_in[4];
  const float* W2 = (const float*)d_in[5];
  const float* b2 = (const float*)d_in[6];
  float* out = (float*)d_out;
  char* ws = (char*)d_ws;

  int*   counts  = (int*)(ws + WS_COUNTS);
  int*   cursors = (int*)(ws + WS_CURSORS);
  int*   padoff  = (int*)(ws + WS_PADOFF);
  int*   meta    = (int*)(ws + WS_META);
  int*   tileE   = (int*)(ws + WS_TILE_E);
  float* pp      = (float*)(ws + WS_PP);
  int*   top_e   = (int*)(ws + WS_TOP_E);
  float* top_w   = (float*)(ws + WS_TOP_W);
  float* slot_w  = (float*)(ws + WS_SLOT_W);
  int*   tok_slot= (int*)(ws + WS_TOK_SLOT);
  unsigned short* Xg = (unsigned short*)(ws + WS_XG);
  unsigned short* Hb = (unsigned short*)(ws + WS_HB);
  unsigned short* Wb = (unsigned short*)(ws + WS_WB);
  unsigned short* Yb = Xg;   // Xg is dead after GEMM1

  hipFuncSetAttribute((const void*)moe_gemm8<D_MODEL, EXP_D, false>,
                      hipFuncAttributeMaxDynamicSharedMemorySize, LDS_TOTAL);
  hipFuncSetAttribute((const void*)moe_gemm8<EXP_D, D_MODEL, true>,
                      hipFuncAttributeMaxDynamicSharedMemorySize, LDS_TOTAL);

  init_kernel<<<dim3(1), dim3(64), 0, stream>>>((int*)ws);
  router_kernel<<<dim3(NTOK/4), dim3(256), 0, stream>>>(x, Wr, br, counts, top_e, top_w, pp);
  prefix_kernel<<<dim3(1), dim3(256), 0, stream>>>((int*)ws, pp, out + (size_t)NTOK*D_MODEL);
  scatgath_kernel<<<dim3(NTOK/4), dim3(256), 0, stream>>>(x, top_e, top_w, cursors, padoff,
                                                          slot_w, tok_slot, Xg);
  cvt_kernel<<<dim3(2048), dim3(256), 0, stream>>>(W1, Wb);
  moe_gemm8<D_MODEL, EXP_D, false><<<dim3((EXP_D/256)*MAX_TILES), dim3(512), LDS_TOTAL, stream>>>(
      Xg, Wb, b1, Hb, tileE, meta, slot_w);
  cvt_kernel<<<dim3(2048), dim3(256), 0, stream>>>(W2, Wb);
  moe_gemm8<EXP_D, D_MODEL, true><<<dim3((D_MODEL/256)*MAX_TILES), dim3(512), LDS_TOTAL, stream>>>(
      Hb, Wb, b2, Yb, tileE, meta, slot_w);
  combine_kernel<<<dim3(NTOK), dim3(256), 0, stream>>>(Yb, tok_slot, out);
}

// Round 4
// 735.538 us; speedup vs baseline: 2.0715x; 2.0715x over previous
//
#include <hip/hip_runtime.h>
#include <stdint.h>

#define D_MODEL 1024
#define EXP_D   4096
#define NE      8
#define NTOK    8192
#define BMT     128
#define MAX_TILES 136
#define NS_MAX  17408   // MAX_TILES*128

typedef __attribute__((ext_vector_type(8))) short short8;
typedef __attribute__((ext_vector_type(4))) float f32x4;
typedef __attribute__((ext_vector_type(4))) unsigned short us4;

// ---- workspace layout (bytes) ----
#define WS_COUNTS    0          // int[8]
#define WS_CURSORS   32         // int[8]
#define WS_PADOFF    64         // int[16]
#define WS_META      128        // int[32], meta[0]=ntiles
#define WS_TILE_E    256        // int[256]
#define WS_PP        4096       // float[2048*8]
#define WS_TOP_E     69632      // int[16384]
#define WS_TOP_W     135168     // float[16384]
#define WS_SLOT_W    270336     // float[17408]
#define WS_TOK_SLOT  339968     // int[16384]
#define WS_XG        405504     // bf16 [17408][1024]  (Yb aliases this)
#define WS_HB        36057088   // bf16 [17408][4096]
#define WS_WB        178663424  // bf16 [8][4096][1024] weights -> ends 245,772,288

#define LDSBUF 49152            // 48KB per buffer: A 16KB + B 32KB
#define LDS_TOTAL 147456        // 3 buffers

__device__ __forceinline__ unsigned short f2bf(float f){
  __bf16 h = (__bf16)f;
  return __builtin_bit_cast(unsigned short, h);
}
__device__ __forceinline__ float bf2f(unsigned short u){
  unsigned int v = ((unsigned int)u) << 16;
  return __builtin_bit_cast(float, v);
}
__device__ __forceinline__ void gl_lds16(const void* g, void* l){
  __builtin_amdgcn_global_load_lds((const __attribute__((address_space(1))) unsigned int*)g,
                                   (__attribute__((address_space(3))) unsigned int*)l,
                                   16, 0, 0);
}

// ---------------- init: zero 64-int header ----------------
__global__ void init_kernel(int* __restrict__ hdr){
  if (threadIdx.x < 64) hdr[threadIdx.x] = 0;
}

// ---------------- weight fp32 -> bf16 convert ----------------
__global__ __launch_bounds__(256) void cvt_kernel(const float* __restrict__ W,
                                                  unsigned short* __restrict__ Wb){
  const int n4 = NE*EXP_D*D_MODEL/4;
  for (int i = blockIdx.x*256 + threadIdx.x; i < n4; i += gridDim.x*256){
    const float4 v = *(const float4*)&W[(size_t)i*4];
    us4 o; o[0]=f2bf(v.x); o[1]=f2bf(v.y); o[2]=f2bf(v.z); o[3]=f2bf(v.w);
    *(us4*)&Wb[(size_t)i*4] = o;
  }
}

// ---------------- router: one wave per token ----------------
__global__ __launch_bounds__(256) void router_kernel(
    const float* __restrict__ x, const float* __restrict__ Wr,
    const float* __restrict__ br,
    int* __restrict__ counts, int* __restrict__ top_e, float* __restrict__ top_w,
    float* __restrict__ pp)
{
  __shared__ float WrS[NE*D_MODEL];
  __shared__ float wprob[4][NE];
  const int tid = threadIdx.x;
#pragma unroll
  for (int i=0;i<8;++i){
    int j = (tid + i*256)*4;
    *(float4*)&WrS[j] = *(const float4*)&Wr[j];
  }
  __syncthreads();
  const int w = tid>>6, lane = tid&63;
  const int t = blockIdx.x*4 + w;
  const float* xt = x + (size_t)t*D_MODEL;
  float accv[8] = {0,0,0,0,0,0,0,0};
#pragma unroll
  for (int i=0;i<4;++i){
    const int k = i*256 + lane*4;
    const float4 xv = *(const float4*)&xt[k];
#pragma unroll
    for (int e=0;e<8;++e){
      const float4 wv = *(const float4*)&WrS[e*D_MODEL + k];
      accv[e] += xv.x*wv.x + xv.y*wv.y + xv.z*wv.z + xv.w*wv.w;
    }
  }
#pragma unroll
  for (int m=32;m>0;m>>=1){
#pragma unroll
    for (int e=0;e<8;++e) accv[e] += __shfl_xor(accv[e], m, 64);
  }
  if (lane==0){
    float lg[8];
#pragma unroll
    for (int e=0;e<8;++e) lg[e] = accv[e] + br[e];
    float mx = lg[0];
#pragma unroll
    for (int e=1;e<8;++e) mx = fmaxf(mx, lg[e]);
    float p[8]; float s=0.f;
#pragma unroll
    for (int e=0;e<8;++e){ p[e] = __expf(lg[e]-mx); s += p[e]; }
    const float inv = 1.f/s;
#pragma unroll
    for (int e=0;e<8;++e){ p[e] *= inv; wprob[w][e] = p[e]; }
    int i1=0; float p1v=p[0];
#pragma unroll
    for (int e=1;e<8;++e) if (p[e] > p1v){ p1v=p[e]; i1=e; }
    int i2=-1; float p2v=-1.f;
#pragma unroll
    for (int e=0;e<8;++e) if (e!=i1 && p[e] > p2v){ p2v=p[e]; i2=e; }
    const float rn = 1.f/(p1v+p2v);
    top_e[2*t]   = i1; top_w[2*t]   = p1v*rn;
    top_e[2*t+1] = i2; top_w[2*t+1] = p2v*rn;
    atomicAdd(&counts[i1],1);
    atomicAdd(&counts[i2],1);
  }
  __syncthreads();
  if (tid<8){
    pp[blockIdx.x*8+tid] = wprob[0][tid]+wprob[1][tid]+wprob[2][tid]+wprob[3][tid];
  }
}

// ---------------- prefix: tile table + aux loss ----------------
__global__ void prefix_kernel(int* __restrict__ wsI, const float* __restrict__ pp,
                              float* __restrict__ aux_out){
  const int tid = threadIdx.x;
  __shared__ float dev2[8];
  if (tid==0){
    int* counts = wsI + 0;
    int* padoff = wsI + 16;
    int* meta   = wsI + 32;
    int* tileE  = wsI + 64;
    int nt = 0;
    for (int e=0;e<NE;++e){
      padoff[e] = nt*BMT;
      int tiles = (counts[e] + BMT - 1) >> 7;
      for (int i=0;i<tiles;++i) tileE[nt++] = e;
    }
    meta[0] = nt;
  }
  if (tid<8){
    float s=0.f;
    for (int b=0;b<NTOK/4;++b) s += pp[b*8+tid];
    float d = s*(1.f/(float)NTOK) - 0.125f;
    dev2[tid] = d*d;
  }
  __syncthreads();
  if (tid==0){
    float a=0.f;
#pragma unroll
    for (int e=0;e<8;++e) a += dev2[e];
    aux_out[0] = a;
  }
}

// ---------------- scatter: LDS-aggregated atomics (64 global RMWs total) ----------------
__global__ __launch_bounds__(1024) void scatter_kernel(
    const int* __restrict__ top_e, const float* __restrict__ top_w,
    int* __restrict__ cursors, const int* __restrict__ padoff,
    float* __restrict__ slot_w, int* __restrict__ tok_slot)
{
  __shared__ int cnt[NE];
  __shared__ int base[NE];
  const int tid = threadIdx.x;
  if (tid < NE) cnt[tid] = 0;
  __syncthreads();
  const int t = blockIdx.x*1024 + tid;
  const int e0 = top_e[2*t], e1 = top_e[2*t+1];
  const float w0v = top_w[2*t], w1v = top_w[2*t+1];
  const int p0 = atomicAdd(&cnt[e0], 1);
  const int p1 = atomicAdd(&cnt[e1], 1);
  __syncthreads();
  if (tid < NE) base[tid] = atomicAdd(&cursors[tid], cnt[tid]);
  __syncthreads();
  const int s0 = padoff[e0] + base[e0] + p0;
  const int s1 = padoff[e1] + base[e1] + p1;
  slot_w[s0] = w0v; slot_w[s1] = w1v;
  tok_slot[2*t] = s0; tok_slot[2*t+1] = s1;
}

// ---------------- gather: wave per token, copy x row to both slots ----------------
__global__ __launch_bounds__(256) void gather_kernel(
    const float* __restrict__ x, const int* __restrict__ tok_slot,
    unsigned short* __restrict__ Xg)
{
  const int w = threadIdx.x>>6, lane = threadIdx.x&63;
  const int t = blockIdx.x*4 + w;
  const int s0 = tok_slot[2*t], s1 = tok_slot[2*t+1];
  us4 o[4];
#pragma unroll
  for (int i=0;i<4;++i){
    const float4 v = *(const float4*)&x[(size_t)t*D_MODEL + i*256 + lane*4];
    o[i][0]=f2bf(v.x); o[i][1]=f2bf(v.y); o[i][2]=f2bf(v.z); o[i][3]=f2bf(v.w);
  }
#pragma unroll
  for (int i=0;i<4;++i) *(us4*)&Xg[(size_t)s0*D_MODEL + i*256 + lane*4] = o[i];
#pragma unroll
  for (int i=0;i<4;++i) *(us4*)&Xg[(size_t)s1*D_MODEL + i*256 + lane*4] = o[i];
}

// ---------------- grouped GEMM: 128x256 tile, BK=64, 8 waves, 3-buf pipeline ----------------
// C[m][n] = sum_k A[m][k] * W[e][n][k]  (+bias; G1: relu; G2: *slot_w[m])
#define VM6   asm volatile("s_waitcnt vmcnt(6)" ::: "memory")
#define VM0   asm volatile("s_waitcnt vmcnt(0)" ::: "memory")
#define LGKM0 do{ asm volatile("s_waitcnt lgkmcnt(0)" ::: "memory"); __builtin_amdgcn_sched_barrier(0); }while(0)
#define FENCE asm volatile("" ::: "memory")

template<int KT, int NT, bool G2>
__global__ __launch_bounds__(512,1) void moe_gemm8(
    const unsigned short* __restrict__ A,
    const unsigned short* __restrict__ Wb,
    const float* __restrict__ bias,
    unsigned short* __restrict__ Cout,
    const int* __restrict__ tileE,
    const int* __restrict__ meta,
    const float* __restrict__ slotw)
{
  constexpr int NX = NT/256;
  constexpr int TOTAL = NX*MAX_TILES;
  constexpr int Q = TOTAL/8, R = TOTAL%8;
  constexpr int NTILES = KT/64;
  // bijective XCD chunk swizzle (N-fastest within chunk -> A-tile L2 reuse)
  const int lid = blockIdx.x;
  const int xc = lid & 7, jj = lid >> 3;
  const int tsw = xc*Q + (xc < R ? xc : R) + jj;
  const int mtile = tsw / NX, ntile = tsw - mtile*NX;
  if (mtile >= meta[0]) return;

  extern __shared__ char smem[];
  const int tid  = threadIdx.x;
  const int w    = tid >> 6, lane = tid & 63;
  const int e    = tileE[mtile];
  const int m0   = mtile * BMT;
  const int n0   = ntile * 256;

  // staging: per instr, wave w covers rows base+w*8+(lane>>3); 16B chunk (lane&7)
  // LDS linear; global source pre-swizzled: logical chunk = phys ^ (row&7), row&7 = lane>>3
  const int srow = w*8 + (lane>>3);
  const int scol = ((lane&7) ^ (lane>>3)) * 8;   // elements
  const unsigned short* Aps = A  + (size_t)(m0 + srow)*KT + scol;
  const unsigned short* Bps = Wb + (size_t)e*NT*KT + (size_t)(n0 + srow)*KT + scol;

#define STG3A(bufc, kbe) do{ \
    gl_lds16(Aps + (kbe),                smem + (size_t)(bufc)*LDSBUF + (w*8)*128); \
    gl_lds16(Aps + (size_t)64*KT + (kbe), smem + (size_t)(bufc)*LDSBUF + (64 + w*8)*128); \
    gl_lds16(Bps + (kbe),                smem + (size_t)(bufc)*LDSBUF + 16384 + (w*8)*128); \
  }while(0)
#define STG3B(bufc, kbe) do{ \
    gl_lds16(Bps + (size_t)64*KT  + (kbe), smem + (size_t)(bufc)*LDSBUF + 16384 + (64  + w*8)*128); \
    gl_lds16(Bps + (size_t)128*KT + (kbe), smem + (size_t)(bufc)*LDSBUF + 16384 + (128 + w*8)*128); \
    gl_lds16(Bps + (size_t)192*KT + (kbe), smem + (size_t)(bufc)*LDSBUF + 16384 + (192 + w*8)*128); \
  }while(0)

  // fragment read addressing
  const int wm = w >> 2, wn = w & 3;       // 2M x 4N waves, per-wave 64x64
  const int r16 = lane & 15, kg = lane >> 4, l7 = lane & 7;
  const int aoff = (wm*64 + r16)*128;          // + fm*2048 + chunk*16
  const int boff = 16384 + (wn*64 + r16)*128;  // + fc*2048 + chunk*16

  f32x4 acc[4][4];
#pragma unroll
  for (int i=0;i<4;++i)
#pragma unroll
    for (int j=0;j<4;++j) acc[i][j] = (f32x4){0.f,0.f,0.f,0.f};

#define PHASE(sb, KK, STG_STMT, WAIT_STMT) do{ \
    const int ch = (((KK)*4 + kg) ^ l7) * 16; \
    short8 af0 = *(const short8*)((sb) + aoff + 0*2048 + ch); \
    short8 af1 = *(const short8*)((sb) + aoff + 1*2048 + ch); \
    short8 af2 = *(const short8*)((sb) + aoff + 2*2048 + ch); \
    short8 af3 = *(const short8*)((sb) + aoff + 3*2048 + ch); \
    short8 bv0 = *(const short8*)((sb) + boff + 0*2048 + ch); \
    short8 bv1 = *(const short8*)((sb) + boff + 1*2048 + ch); \
    short8 bv2 = *(const short8*)((sb) + boff + 2*2048 + ch); \
    short8 bv3 = *(const short8*)((sb) + boff + 3*2048 + ch); \
    STG_STMT; WAIT_STMT; FENCE; \
    __builtin_amdgcn_s_barrier(); \
    LGKM0; \
    __builtin_amdgcn_s_setprio(1); \
    acc[0][0]=__builtin_amdgcn_mfma_f32_16x16x32_bf16(bv0,af0,acc[0][0],0,0,0); \
    acc[0][1]=__builtin_amdgcn_mfma_f32_16x16x32_bf16(bv1,af0,acc[0][1],0,0,0); \
    acc[0][2]=__builtin_amdgcn_mfma_f32_16x16x32_bf16(bv2,af0,acc[0][2],0,0,0); \
    acc[0][3]=__builtin_amdgcn_mfma_f32_16x16x32_bf16(bv3,af0,acc[0][3],0,0,0); \
    acc[1][0]=__builtin_amdgcn_mfma_f32_16x16x32_bf16(bv0,af1,acc[1][0],0,0,0); \
    acc[1][1]=__builtin_amdgcn_mfma_f32_16x16x32_bf16(bv1,af1,acc[1][1],0,0,0); \
    acc[1][2]=__builtin_amdgcn_mfma_f32_16x16x32_bf16(bv2,af1,acc[1][2],0,0,0); \
    acc[1][3]=__builtin_amdgcn_mfma_f32_16x16x32_bf16(bv3,af1,acc[1][3],0,0,0); \
    acc[2][0]=__builtin_amdgcn_mfma_f32_16x16x32_bf16(bv0,af2,acc[2][0],0,0,0); \
    acc[2][1]=__builtin_amdgcn_mfma_f32_16x16x32_bf16(bv1,af2,acc[2][1],0,0,0); \
    acc[2][2]=__builtin_amdgcn_mfma_f32_16x16x32_bf16(bv2,af2,acc[2][2],0,0,0); \
    acc[2][3]=__builtin_amdgcn_mfma_f32_16x16x32_bf16(bv3,af2,acc[2][3],0,0,0); \
    acc[3][0]=__builtin_amdgcn_mfma_f32_16x16x32_bf16(bv0,af3,acc[3][0],0,0,0); \
    acc[3][1]=__builtin_amdgcn_mfma_f32_16x16x32_bf16(bv1,af3,acc[3][1],0,0,0); \
    acc[3][2]=__builtin_amdgcn_mfma_f32_16x16x32_bf16(bv2,af3,acc[3][2],0,0,0); \
    acc[3][3]=__builtin_amdgcn_mfma_f32_16x16x32_bf16(bv3,af3,acc[3][3],0,0,0); \
    __builtin_amdgcn_s_setprio(0); \
    __builtin_amdgcn_sched_barrier(0); \
    __builtin_amdgcn_s_barrier(); \
  }while(0)

  // prologue: stage tiles 0 and 1
  STG3A(0, 0); STG3B(0, 0);
  STG3A(1, 64); STG3B(1, 64);
  VM6; FENCE;
  __builtin_amdgcn_s_barrier();

  int cur = 0, stg = 2;
  for (int tt = 0; tt < NTILES-2; ++tt){
    const int kbn = (tt+2)*64;
    const char* sb = smem + (size_t)cur*LDSBUF;
    PHASE(sb, 0, STG3A(stg, kbn), (void)0);
    PHASE(sb, 1, STG3B(stg, kbn), VM6);
    cur = (cur==2)?0:cur+1;
    stg = (stg==2)?0:stg+1;
  }
  { // tile NTILES-2: no stage; drain remaining loads at ph1
    const char* sb = smem + (size_t)cur*LDSBUF;
    PHASE(sb, 0, (void)0, (void)0);
    PHASE(sb, 1, (void)0, VM0);
    cur = (cur==2)?0:cur+1;
  }
  { // tile NTILES-1: no stage, no wait
    const char* sb = smem + (size_t)cur*LDSBUF;
    PHASE(sb, 0, (void)0, (void)0);
    PHASE(sb, 1, (void)0, (void)0);
  }

  // epilogue: lane holds 4 consecutive n per fragment (swapped-operand layout)
  const int mrow = lane & 15, ng4 = (lane >> 4)*4;
#pragma unroll
  for (int fm=0; fm<4; ++fm){
    const int m = m0 + wm*64 + fm*16 + mrow;
    float wg = 0.f;
    if (G2) wg = slotw[m];
#pragma unroll
    for (int fc=0; fc<4; ++fc){
      const int nb = n0 + wn*64 + fc*16 + ng4;
      const float4 bv = *(const float4*)&bias[(size_t)e*NT + nb];
      float q0 = acc[fm][fc][0] + bv.x;
      float q1 = acc[fm][fc][1] + bv.y;
      float q2 = acc[fm][fc][2] + bv.z;
      float q3 = acc[fm][fc][3] + bv.w;
      if (!G2){
        q0=fmaxf(q0,0.f); q1=fmaxf(q1,0.f); q2=fmaxf(q2,0.f); q3=fmaxf(q3,0.f);
      } else {
        q0*=wg; q1*=wg; q2*=wg; q3*=wg;
      }
      us4 o; o[0]=f2bf(q0); o[1]=f2bf(q1); o[2]=f2bf(q2); o[3]=f2bf(q3);
      *(us4*)&Cout[(size_t)m*NT + nb] = o;
    }
  }
#undef PHASE
#undef STG3A
#undef STG3B
}

// ---------------- combine: out[t] = Y[slot0] + Y[slot1] ----------------
__global__ __launch_bounds__(256) void combine_kernel(
    const unsigned short* __restrict__ Yb, const int* __restrict__ tok_slot,
    float* __restrict__ out)
{
  const int t = blockIdx.x;
  const int tid = threadIdx.x;
  const int s0 = tok_slot[2*t], s1 = tok_slot[2*t+1];
  const us4 a = *(const us4*)&Yb[(size_t)s0*D_MODEL + tid*4];
  const us4 b = *(const us4*)&Yb[(size_t)s1*D_MODEL + tid*4];
  float4 o;
  o.x = bf2f(a[0]) + bf2f(b[0]);
  o.y = bf2f(a[1]) + bf2f(b[1]);
  o.z = bf2f(a[2]) + bf2f(b[2]);
  o.w = bf2f(a[3]) + bf2f(b[3]);
  *(float4*)&out[(size_t)t*D_MODEL + tid*4] = o;
}

extern "C" void kernel_launch(void* const* d_in, const int* in_sizes, int n_in,
                              void* d_out, int out_size, void* d_ws, size_t ws_size,
                              hipStream_t stream)
{
  const float* x  = (const float*)d_in[0];
  const float* Wr = (const float*)d_in[1];
  const float* br = (const float*)d_in[2];
  const float* W1 = (const float*)d_in[3];
  const float* b1 = (const float*)d_in[4];
  const float* W2 = (const float*)d_in[5];
  const float* b2 = (const float*)d_in[6];
  float* out = (float*)d_out;
  char* ws = (char*)d_ws;

  int*   counts  = (int*)(ws + WS_COUNTS);
  int*   cursors = (int*)(ws + WS_CURSORS);
  int*   padoff  = (int*)(ws + WS_PADOFF);
  int*   meta    = (int*)(ws + WS_META);
  int*   tileE   = (int*)(ws + WS_TILE_E);
  float* pp      = (float*)(ws + WS_PP);
  int*   top_e   = (int*)(ws + WS_TOP_E);
  float* top_w   = (float*)(ws + WS_TOP_W);
  float* slot_w  = (float*)(ws + WS_SLOT_W);
  int*   tok_slot= (int*)(ws + WS_TOK_SLOT);
  unsigned short* Xg = (unsigned short*)(ws + WS_XG);
  unsigned short* Hb = (unsigned short*)(ws + WS_HB);
  unsigned short* Wb = (unsigned short*)(ws + WS_WB);
  unsigned short* Yb = Xg;   // Xg is dead after GEMM1

  hipFuncSetAttribute((const void*)moe_gemm8<D_MODEL, EXP_D, false>,
                      hipFuncAttributeMaxDynamicSharedMemorySize, LDS_TOTAL);
  hipFuncSetAttribute((const void*)moe_gemm8<EXP_D, D_MODEL, true>,
                      hipFuncAttributeMaxDynamicSharedMemorySize, LDS_TOTAL);

  init_kernel<<<dim3(1), dim3(64), 0, stream>>>((int*)ws);
  router_kernel<<<dim3(NTOK/4), dim3(256), 0, stream>>>(x, Wr, br, counts, top_e, top_w, pp);
  prefix_kernel<<<dim3(1), dim3(256), 0, stream>>>((int*)ws, pp, out + (size_t)NTOK*D_MODEL);
  scatter_kernel<<<dim3(NTOK/1024), dim3(1024), 0, stream>>>(top_e, top_w, cursors, padoff,
                                                             slot_w, tok_slot);
  gather_kernel<<<dim3(NTOK/4), dim3(256), 0, stream>>>(x, tok_slot, Xg);
  cvt_kernel<<<dim3(2048), dim3(256), 0, stream>>>(W1, Wb);
  moe_gemm8<D_MODEL, EXP_D, false><<<dim3((EXP_D/256)*MAX_TILES), dim3(512), LDS_TOTAL, stream>>>(
      Xg, Wb, b1, Hb, tileE, meta, slot_w);
  cvt_kernel<<<dim3(2048), dim3(256), 0, stream>>>(W2, Wb);
  moe_gemm8<EXP_D, D_MODEL, true><<<dim3((D_MODEL/256)*MAX_TILES), dim3(512), LDS_TOTAL, stream>>>(
      Hb, Wb, b2, Yb, tileE, meta, slot_w);
  combine_kernel<<<dim3(NTOK), dim3(256), 0, stream>>>(Yb, tok_slot, out);
}